// Round 2
// baseline (362.289 us; speedup 1.0000x reference)
//
#include <hip/hip_runtime.h>

#define B_ 64
#define N_ 4096
#define C_ 10
#define D_ 8
#define E_ 16
#define EPS_ 1e-7f

__device__ inline float reduce16(float v) {
    v += __shfl_xor(v, 1);
    v += __shfl_xor(v, 2);
    v += __shfl_xor(v, 4);
    v += __shfl_xor(v, 8);
    return v;
}

// One block: one (b, chunk). 4 lanes per n (lane owns e-quad l*4..l*4+3).
// 256 threads = 64 n per sweep; npb/64 sweeps.
__global__ __launch_bounds__(256) void caps_pass(
    const float* __restrict__ x, const float* __restrict__ W,
    const float* __restrict__ v_cum, float* __restrict__ partial_s,
    int nchunk, int npb)
{
    const int bid = (int)blockIdx.x;
    int b, chunk;
    if (nchunk >= 8) {
        // XCD-aware: round-robin dispatch puts bid&7 on one XCD; give each
        // XCD a contiguous set of W-chunks (nchunk/8 chunks = ~2.6MB < 4MB L2).
        const int cpx = nchunk >> 3;
        const int xcd = bid & 7;
        const int local = bid >> 3;          // [0, 64*cpx)
        chunk = xcd * cpx + (local >> 6);
        b = local & 63;
    } else {
        b = bid & 63;
        chunk = bid >> 6;
    }

    const int tid = (int)threadIdx.x;
    const int g = tid >> 2;      // group (n slot within sweep), 0..63
    const int l = tid & 3;       // e-quad index

    // v_cum[b] staged in LDS as float4[c][l]
    __shared__ float4 vsh[C_][4];
    if (tid < C_ * 4) {
        ((float4*)vsh)[tid] = ((const float4*)(v_cum + b * C_ * E_))[tid];
    }
    __syncthreads();

    float4 acc[C_];
#pragma unroll
    for (int c = 0; c < C_; ++c) acc[c] = make_float4(0.f, 0.f, 0.f, 0.f);

    for (int i = g; i < npb; i += 64) {
        const int n = chunk * npb + i;
        const float4* xp = (const float4*)(x + ((size_t)b * N_ + n) * D_);
        const float4 x0 = xp[0], x1 = xp[1];
        float xv[D_] = {x0.x, x0.y, x0.z, x0.w, x1.x, x1.y, x1.z, x1.w};

        const float4* Wn = (const float4*)(W + (size_t)n * (C_ * D_ * E_)) + l;

        float4 uh[C_];
#pragma unroll
        for (int c = 0; c < C_; ++c) {
            float4 u = make_float4(0.f, 0.f, 0.f, 0.f);
#pragma unroll
            for (int d = 0; d < D_; ++d) {
                const float4 w = Wn[c * 32 + d * 4];
                u.x = fmaf(xv[d], w.x, u.x);
                u.y = fmaf(xv[d], w.y, u.y);
                u.z = fmaf(xv[d], w.z, u.z);
                u.w = fmaf(xv[d], w.w, u.w);
            }
            uh[c] = u;
        }

        // logits[c] = sum_e uh[c][e]*v_cum[b,c,e]: dot4 + 4-lane reduce
        float logit[C_];
#pragma unroll
        for (int c = 0; c < C_; ++c) {
            const float4 vc = vsh[c][l];
            float t = uh[c].x * vc.x + uh[c].y * vc.y + uh[c].z * vc.z + uh[c].w * vc.w;
            t += __shfl_xor(t, 1);
            t += __shfl_xor(t, 2);
            logit[c] = t;
        }

        // softmax over C (identical across the 4 lanes of the group)
        float m = logit[0];
#pragma unroll
        for (int c = 1; c < C_; ++c) m = fmaxf(m, logit[c]);
        float ssum = 0.f;
        float ec[C_];
#pragma unroll
        for (int c = 0; c < C_; ++c) { ec[c] = __expf(logit[c] - m); ssum += ec[c]; }
        const float inv = 1.f / ssum;
#pragma unroll
        for (int c = 0; c < C_; ++c) {
            const float w = ec[c] * inv;
            acc[c].x = fmaf(w, uh[c].x, acc[c].x);
            acc[c].y = fmaf(w, uh[c].y, acc[c].y);
            acc[c].z = fmaf(w, uh[c].z, acc[c].z);
            acc[c].w = fmaf(w, uh[c].w, acc[c].w);
        }
    }

    // reduce over the 16 groups within each wave (xor 4,8,16,32)
#pragma unroll
    for (int c = 0; c < C_; ++c) {
#pragma unroll
        for (int msk = 4; msk <= 32; msk <<= 1) {
            acc[c].x += __shfl_xor(acc[c].x, msk);
            acc[c].y += __shfl_xor(acc[c].y, msk);
            acc[c].z += __shfl_xor(acc[c].z, msk);
            acc[c].w += __shfl_xor(acc[c].w, msk);
        }
    }
    const int wave = tid >> 6;
    const int lane = tid & 63;
    __shared__ float4 red[4][C_][4];
    if (lane < 4) {
#pragma unroll
        for (int c = 0; c < C_; ++c) red[wave][c][lane] = acc[c];
    }
    __syncthreads();
    if (tid < C_ * E_) {
        const int c = tid >> 4;
        const int e = tid & 15;
        float s = 0.f;
#pragma unroll
        for (int w = 0; w < 4; ++w) s += ((const float*)red[w][c])[e];
        partial_s[(((size_t)b * nchunk + chunk) * C_ + c) * E_ + e] = s;
    }
}

// One block per b: sum partials over chunks, squash, update v_cum or write out.
__global__ __launch_bounds__(192) void caps_reduce(
    const float* __restrict__ partial_s, float* __restrict__ v_cum,
    float* __restrict__ out, int nchunk, int last)
{
    const int b = (int)blockIdx.x;
    const int tid = (int)threadIdx.x;
    if (tid >= C_ * E_) return;
    const int c = tid >> 4;
    const int e = tid & 15;
    float s = 0.f;
    for (int k = 0; k < nchunk; ++k)
        s += partial_s[(((size_t)b * nchunk + k) * C_ + c) * E_ + e];
    const float s2 = reduce16(s * s);
    const float scale = (s2 / (1.f + s2)) * rsqrtf(s2 + EPS_);
    const float v = scale * s;
    if (last) out[(b * C_ + c) * E_ + e] = v;
    else      v_cum[(b * C_ + c) * E_ + e] += v;
}

extern "C" void kernel_launch(void* const* d_in, const int* in_sizes, int n_in,
                              void* d_out, int out_size, void* d_ws, size_t ws_size,
                              hipStream_t stream) {
    const float* x = (const float*)d_in[0];
    const float* W = (const float*)d_in[1];
    float* out = (float*)d_out;

    const size_t vbytes = (size_t)B_ * C_ * E_ * sizeof(float);  // 40 KB
    float* v_cum = (float*)d_ws;
    float* partial = (float*)((char*)d_ws + vbytes);

    int nchunk = 32;
    while (nchunk > 1 &&
           vbytes + (size_t)B_ * nchunk * C_ * E_ * sizeof(float) > ws_size)
        nchunk >>= 1;
    const int npb = N_ / nchunk;

    hipMemsetAsync(v_cum, 0, vbytes, stream);
    for (int t = 0; t < 3; ++t) {
        caps_pass<<<dim3(B_ * nchunk), 256, 0, stream>>>(x, W, v_cum, partial, nchunk, npb);
        caps_reduce<<<B_, 192, 0, stream>>>(partial, v_cum, out, nchunk, t == 2);
    }
}